// Round 1
// 111.430 us; speedup vs baseline: 1.0094x; 1.0094x over previous
//
#include <hip/hip_runtime.h>

#define IMG_H 200
#define IMG_W 200
#define VOLD  256          // volume is 256^3, strides: x<<16, y<<8, z
#define KPH   8            // threads (phases) per pixel
#define PPB   (256 / KPH)  // 32 pixels per 256-thread block
#define NPIX  (IMG_H * IMG_W)
#define NBLK  (NPIX / PPB) // 1250 (exact)
#define NXCD  8

__global__ __launch_bounds__(256) void drr_kernel(
    const float* __restrict__ vol,
    const float* __restrict__ kinv,   // [3][3]
    const float* __restrict__ rt,     // [4][4]
    const float* __restrict__ sddp,   // [1]
    const float* __restrict__ aff,    // [4][4]
    const int*   __restrict__ nsp,    // [1]
    float*       __restrict__ out)    // [H*W]
{
    // ---- bijective XCD-chunked swizzle (m204 form): each XCD gets a
    // contiguous chunk of blocks => contiguous detector rows => a ~1.9MB
    // y-slab of the volume that fits its private 4MB L2.
    int b = blockIdx.x;
    {
        const int q = NBLK / NXCD;          // 156
        const int r = NBLK % NXCD;          // 2
        const int xcd = b % NXCD;
        const int idx = b / NXCD;
        b = (xcd < r) ? xcd * (q + 1) + idx
                      : r * (q + 1) + (xcd - r) * q + idx;
    }

    const int p     = b * PPB + ((int)threadIdx.x >> 3);  // pixel index
    const int phase = (int)threadIdx.x & (KPH - 1);
    if (p >= NPIX) return;   // never true (40000 exact), keeps compiler honest

    const int   N     = nsp[0];
    const float sdd   = sddp[0];
    const float invN1 = 1.0f / (float)(N - 1);

    const float u = (float)(p % IMG_W);
    const float v = (float)(p / IMG_W);

    // tgt_cam = K^-1 * (u,v,1) * sdd
    const float tcx = (kinv[0]*u + kinv[1]*v + kinv[2]) * sdd;
    const float tcy = (kinv[3]*u + kinv[4]*v + kinv[5]) * sdd;
    const float tcz = (kinv[6]*u + kinv[7]*v + kinv[8]) * sdd;

    // ray = R * tgt_cam ; src = t
    const float rx = rt[0]*tcx + rt[1]*tcy + rt[2]*tcz;
    const float ry = rt[4]*tcx + rt[5]*tcy + rt[6]*tcz;
    const float rz = rt[8]*tcx + rt[9]*tcy + rt[10]*tcz;
    const float sx = rt[3], sy = rt[7], sz = rt[11];

    // voxel-space: vox(t) = base + t * dir
    const float bx = aff[0]*sx + aff[1]*sy + aff[2]*sz  + aff[3];
    const float by = aff[4]*sx + aff[5]*sy + aff[6]*sz  + aff[7];
    const float bz = aff[8]*sx + aff[9]*sy + aff[10]*sz + aff[11];
    const float dx = aff[0]*rx + aff[1]*ry + aff[2]*rz;
    const float dy = aff[4]*rx + aff[5]*ry + aff[6]*rz;
    const float dz = aff[8]*rx + aff[9]*ry + aff[10]*rz;

    // ---- ray/box culling: sample is nonzero only if all coords in (-1, 256)
    // rcp instead of IEEE divide: result feeds floor/ceil with a +/-2 sample
    // margin, so ~1ulp rcp error is harmless.
    float t0 = 0.0f, t1 = 1.0f;
    {
        const float lo = -1.0f, hi = (float)VOLD;
        const float bs[3] = {bx, by, bz};
        const float ds[3] = {dx, dy, dz};
        #pragma unroll
        for (int d = 0; d < 3; ++d) {
            const float bq = bs[d];
            const float dd = ds[d];
            if (fabsf(dd) > 1e-20f) {
                const float rdd = __frcp_rn(dd);
                const float ta = (lo - bq) * rdd;
                const float tb = (hi - bq) * rdd;
                t0 = fmaxf(t0, fminf(ta, tb));
                t1 = fminf(t1, fmaxf(ta, tb));
            } else if (bq <= lo || bq >= hi) {
                t0 = 1.0f; t1 = -1.0f;   // empty
            }
        }
    }
    int s_lo = 0, s_hi = -1;
    if (t0 <= t1) {
        s_lo = (int)floorf(t0 * (float)(N - 1)) - 2;
        s_hi = (int)ceilf (t1 * (float)(N - 1)) + 2;
        s_lo = max(s_lo, 0);
        s_hi = min(s_hi, N - 1);
    }

    float acc = 0.0f;
    #pragma unroll 4
    for (int s = s_lo + phase; s <= s_hi; s += KPH) {
        const float t = (float)s * invN1;
        const float x = fmaf(t, dx, bx);
        const float y = fmaf(t, dy, by);
        const float z = fmaf(t, dz, bz);
        const float fx = floorf(x), fy = floorf(y), fz = floorf(z);
        const int ix = (int)fx, iy = (int)fy, iz = (int)fz;
        const float wx = x - fx, wy = y - fy, wz = z - fz;

        float c000, c001, c010, c011, c100, c101, c110, c111;
        if ((unsigned)ix < 255u && (unsigned)iy < 255u && (unsigned)iz < 255u) {
            // fully interior: all 8 corners valid; pairs in z merge to dwordx2
            const float* pb = vol + ((ix << 16) + (iy << 8) + iz);
            c000 = pb[0];         c001 = pb[1];
            c010 = pb[256];       c011 = pb[257];
            c100 = pb[65536];     c101 = pb[65537];
            c110 = pb[65536+256]; c111 = pb[65536+257];
        } else {
            const bool x0 = (unsigned)ix       < 256u;
            const bool x1 = (unsigned)(ix + 1) < 256u;
            const bool y0 = (unsigned)iy       < 256u;
            const bool y1 = (unsigned)(iy + 1) < 256u;
            const bool z0 = (unsigned)iz       < 256u;
            const bool z1 = (unsigned)(iz + 1) < 256u;
            const int bx0 = ix << 16, bx1 = (ix + 1) << 16;
            const int by0 = iy << 8,  by1 = (iy + 1) << 8;
            c000 = (x0 && y0 && z0) ? vol[bx0 + by0 + iz]     : 0.0f;
            c001 = (x0 && y0 && z1) ? vol[bx0 + by0 + iz + 1] : 0.0f;
            c010 = (x0 && y1 && z0) ? vol[bx0 + by1 + iz]     : 0.0f;
            c011 = (x0 && y1 && z1) ? vol[bx0 + by1 + iz + 1] : 0.0f;
            c100 = (x1 && y0 && z0) ? vol[bx1 + by0 + iz]     : 0.0f;
            c101 = (x1 && y0 && z1) ? vol[bx1 + by0 + iz + 1] : 0.0f;
            c110 = (x1 && y1 && z0) ? vol[bx1 + by1 + iz]     : 0.0f;
            c111 = (x1 && y1 && z1) ? vol[bx1 + by1 + iz + 1] : 0.0f;
        }

        const float c00 = fmaf(wz, c001 - c000, c000);
        const float c01 = fmaf(wz, c011 - c010, c010);
        const float c10 = fmaf(wz, c101 - c100, c100);
        const float c11 = fmaf(wz, c111 - c110, c110);
        const float c0  = fmaf(wy, c01 - c00, c00);
        const float c1  = fmaf(wy, c11 - c10, c10);
        acc += fmaf(wx, c1 - c0, c0);
    }

    // reduce the 8 phases of this pixel (contiguous lanes)
    acc += __shfl_down(acc, 4, KPH);
    acc += __shfl_down(acc, 2, KPH);
    acc += __shfl_down(acc, 1, KPH);

    if (phase == 0) {
        const float step = sqrtf(rx*rx + ry*ry + rz*rz) * invN1;
        out[p] = acc * step;
    }
}

extern "C" void kernel_launch(void* const* d_in, const int* in_sizes, int n_in,
                              void* d_out, int out_size, void* d_ws, size_t ws_size,
                              hipStream_t stream) {
    const float* vol  = (const float*)d_in[0];
    const float* kinv = (const float*)d_in[1];
    const float* rt   = (const float*)d_in[2];
    const float* sdd  = (const float*)d_in[3];
    const float* aff  = (const float*)d_in[4];
    const int*   nsp  = (const int*)d_in[5];
    float* out = (float*)d_out;

    dim3 block(256);
    dim3 grid(NBLK);   // 1250 blocks * 32 pixels/block = 40000 pixels
    drr_kernel<<<grid, block, 0, stream>>>(vol, kinv, rt, sdd, aff, nsp, out);
}